// Round 1
// baseline (245.370 us; speedup 1.0000x reference)
//
#include <hip/hip_runtime.h>
#include <hip/hip_bf16.h>
#include <math.h>

#define T_TOK 8192
#define DM 1024
#define DE 512
#define NE 8
#define DFF 4096

// converted/derived bf16 buffer layout (element offsets inside conv)
#define CO_X   0
#define CO_W1  8388608   // w1T [8][512][1024]  (always written by transp_k)
#define CO_W2  12582912  // w2T [8][1024][512]
#define CO_B1  16777216
#define CO_B2  16781312
#define CO_CE  16789504
#define CO_WR  16797696
#define CO_TOT 16805888

// workspace byte offsets
// meta ints: [0]=flag, [16..23]=counts, [32..39]=off, [48..55]=cinv (floats)
#define WS_GATE2 256
#define WS_B32   65792
#define WS_TOP2  262400
#define WS_TOK   295168
#define WS_AE    360704
#define WS_AG    426240
#define WS_INV   491776
#define WS_CONV  557312
#define WS_HC    34169088
#define WS_OC    50946304

typedef __attribute__((ext_vector_type(8))) __bf16 bf16x8;
typedef __attribute__((ext_vector_type(4))) __bf16 bf16x4;
typedef __attribute__((ext_vector_type(4))) float f32x4;

__device__ __forceinline__ f32x4 ld4(const void* p, size_t off, int md)
{
  f32x4 r;
  if (md){
    bf16x4 v = *(const bf16x4*)((const __bf16*)p + off);
    #pragma unroll
    for (int j = 0; j < 4; j++) r[j] = (float)v[j];
  } else {
    r = *(const f32x4*)((const float*)p + off);
  }
  return r;
}

// async 16B global -> LDS (dest must be lane-linear: base + lane*16)
__device__ __forceinline__ void async_ld16(const __bf16* g, __bf16* l)
{
  __builtin_amdgcn_global_load_lds(
      (const __attribute__((address_space(1))) unsigned int*)g,
      (__attribute__((address_space(3))) unsigned int*)l, 16, 0, 0);
}

// ---- detect dtype (0=fp32,1=bf16) + centroid inv-norms + zero counts/b32 ----
__global__ __launch_bounds__(256) void detect_k(const void* xp, const void* cp,
                                                int* meta, int* b32)
{
  const int tid = threadIdx.x;
  const float* xf = (const float*)xp;
  int ok = 0;
  for (int i = tid; i < 1024; i += 256){
    float a = fabsf(xf[i]);
    if (a > 1e-8f && a < 100.f) ok++;  // NaN compares false
  }
  __shared__ int cnt;
  __shared__ int flg;
  if (tid == 0) cnt = 0;
  __syncthreads();
  atomicAdd(&cnt, ok);
  __syncthreads();
  if (tid == 0){ flg = (cnt > 512) ? 0 : 1; meta[0] = flg; }
  __syncthreads();
  const int md = flg;

  const int e = tid >> 5, i = tid & 31;
  float ss = 0.f;
  for (int j = 0; j < 32; j++){
    size_t d = (size_t)e * DM + i + j * 32;
    float v = md ? (float)((const __bf16*)cp)[d] : ((const float*)cp)[d];
    ss += v * v;
  }
  #pragma unroll
  for (int m = 1; m < 32; m <<= 1) ss += __shfl_xor(ss, m, 64);
  float* cinv = (float*)(meta + 48);   // bytes 192..223: inside meta region
  if (i == 0) cinv[e] = 1.f / fmaxf(sqrtf(ss), 1e-12f);

  b32[tid] = 0;
  if (tid < 8) meta[16 + tid] = 0;
}

// ---- convert b1/b2/ce/wr tail to bf16 (fp32 mode only; x handled in route) --
__global__ __launch_bounds__(256) void convert_k(
    const float* __restrict__ b1, const float* __restrict__ b2,
    const float* __restrict__ ce, const float* __restrict__ wr,
    __bf16* __restrict__ dst, const int* __restrict__ meta)
{
  if (meta[0]) return;
  const size_t j = ((size_t)blockIdx.x * 256 + threadIdx.x) * 4;  // 0..28668
  const float* src;
  const size_t doff = CO_B1 + j;
  if      (j < 4096)  src = b1 + j;
  else if (j < 12288) src = b2 + (j - 4096);
  else if (j < 20480) src = ce + (j - 12288);
  else                src = wr + (j - 20480);
  f32x4 v = *(const f32x4*)src;
  bf16x4 o;
  #pragma unroll
  for (int t = 0; t < 4; t++) o[t] = (__bf16)v[t];
  *(bf16x4*)(dst + doff) = o;
}

// ---- transpose w1 -> w1T, w2 -> w2T (bf16 out; handles both src dtypes) ----
__global__ __launch_bounds__(256) void transp_k(
    const void* w1q, const void* w2q, __bf16* __restrict__ conv,
    const int* __restrict__ meta)
{
  const int md = meta[0];
  __shared__ __bf16 tile[32][33];
  const int b = blockIdx.x, tid = threadIdx.x;
  const int ty = tid >> 5, tx = tid & 31;

  const void* src; __bf16* dst; int ldS, ldD, i0, j0; size_t soff, doffb;
  if (b < 4096){                       // w1[e]: [1024][512] -> w1T[e]: [512][1024]
    const int e = b >> 9, t = b & 511; // 32 x 16 tiles
    i0 = (t >> 4) << 5; j0 = (t & 15) << 5;
    ldS = DE; ldD = DM;
    soff = (size_t)e * DM * DE;
    dst = conv + CO_W1; doffb = (size_t)e * DE * DM;
    src = md ? (const void*)((const __bf16*)w1q) : (const void*)((const float*)w1q);
  } else {                             // w2[e]: [512][1024] -> w2T[e]: [1024][512]
    const int e = (b - 4096) >> 9, t = (b - 4096) & 511; // 16 x 32 tiles
    i0 = (t >> 5) << 5; j0 = (t & 31) << 5;
    ldS = DM; ldD = DE;
    soff = (size_t)e * DE * DM;
    dst = conv + CO_W2; doffb = (size_t)e * DM * DE;
    src = md ? (const void*)((const __bf16*)w2q) : (const void*)((const float*)w2q);
  }

  #pragma unroll
  for (int rr = 0; rr < 4; rr++){
    const int r = rr * 8 + ty;
    const size_t s = soff + (size_t)(i0 + r) * ldS + j0 + tx;
    tile[r][tx] = md ? ((const __bf16*)src)[s] : (__bf16)((const float*)src)[s];
  }
  __syncthreads();
  #pragma unroll
  for (int rr = 0; rr < 4; rr++){
    const int r = rr * 8 + ty;
    dst[doffb + (size_t)(j0 + r) * ldD + i0 + tx] = tile[tx][r];
  }
}

// ---- routing: 16 lanes/token, 16 tokens/block; also emits x in bf16 --------
__global__ __launch_bounds__(256) void route_k(
    const void* __restrict__ xp, const void* __restrict__ cp,
    const void* __restrict__ wp, const int* __restrict__ meta,
    __bf16* __restrict__ conv, float2* __restrict__ gate2,
    int* __restrict__ top2, int* __restrict__ b32)
{
  const int md = meta[0];
  const float* cinv = (const float*)(meta + 48);
  const int tid = threadIdx.x;
  const int g = tid >> 4, l = tid & 15;
  const int t = blockIdx.x * 16 + g;

  __shared__ int hist[8];
  if (tid < 8) hist[tid] = 0;
  __syncthreads();

  float xx = 0.f, cd[NE], wd[NE];
  #pragma unroll
  for (int e = 0; e < NE; e++){ cd[e] = 0.f; wd[e] = 0.f; }

  const size_t xbase = (size_t)t * DM;
  for (int j = 0; j < 16; j++){
    const int d0 = j * 64 + l * 4;
    f32x4 xv = ld4(xp, xbase + d0, md);
    if (!md){                           // fold x -> bf16 conversion into routing
      bf16x4 o;
      #pragma unroll
      for (int jj = 0; jj < 4; jj++) o[jj] = (__bf16)xv[jj];
      *(bf16x4*)(conv + CO_X + xbase + d0) = o;
    }
    xx += xv[0]*xv[0] + xv[1]*xv[1] + xv[2]*xv[2] + xv[3]*xv[3];
    #pragma unroll
    for (int e = 0; e < NE; e++){
      f32x4 cv = ld4(cp, (size_t)e * DM + d0, md);
      f32x4 wv = ld4(wp, (size_t)e * DM + d0, md);
      cd[e] += xv[0]*cv[0] + xv[1]*cv[1] + xv[2]*cv[2] + xv[3]*cv[3];
      wd[e] += xv[0]*wv[0] + xv[1]*wv[1] + xv[2]*wv[2] + xv[3]*wv[3];
    }
  }
  #pragma unroll
  for (int m = 1; m < 16; m <<= 1){
    xx += __shfl_xor(xx, m, 64);
    #pragma unroll
    for (int e = 0; e < NE; e++){
      cd[e] += __shfl_xor(cd[e], m, 64);
      wd[e] += __shfl_xor(wd[e], m, 64);
    }
  }

  if (l == 0){
    const float rxn = 1.f / fmaxf(sqrtf(xx), 1e-12f);
    float logits[NE];
    #pragma unroll
    for (int e = 0; e < NE; e++) logits[e] = cd[e] * rxn * cinv[e] + wd[e];
    float m1 = -1e30f; int i1 = 0;
    #pragma unroll
    for (int e = 0; e < NE; e++) if (logits[e] > m1){ m1 = logits[e]; i1 = e; }
    float m2 = -1e30f; int i2 = (i1 == 0) ? 1 : 0;
    #pragma unroll
    for (int e = 0; e < NE; e++)
      if (e != i1 && logits[e] > m2){ m2 = logits[e]; i2 = e; }
    float denom = 0.f, ex1 = 0.f, ex2 = 0.f;
    #pragma unroll
    for (int e = 0; e < NE; e++){
      if (logits[e] >= m2){
        float ee = expf(logits[e] - m1);
        denom += ee;
        if (e == i1) ex1 = ee;
        if (e == i2) ex2 = ee;
      }
    }
    const float inv = 1.f / denom;
    gate2[t] = make_float2(ex1 * inv, ex2 * inv);
    top2[t] = i1 | (i2 << 8);
    atomicAdd(&hist[i1], 1);
    atomicAdd(&hist[i2], 1);
  }
  __syncthreads();
  if (tid < 8) atomicAdd(&b32[(blockIdx.x >> 4) * 8 + tid], hist[tid]);
}

// ---- offsets: prefix over 32x8 block counts -> bases + meta ----------------
__global__ void offsets_k(int* meta, int* b32)
{
  const int l = threadIdx.x;
  int running = 0;
  for (int e = 0; e < NE; e++){
    int v = (l < 32) ? b32[l * 8 + e] : 0;
    int incl = v;
    #pragma unroll
    for (int ofs = 1; ofs < 32; ofs <<= 1){
      int n = __shfl_up(incl, ofs, 64);
      if (l >= ofs) incl += n;
    }
    int tot = __shfl(incl, 31, 64);
    if (l < 32) b32[l * 8 + e] = running + (incl - v);
    if (l == 0){ meta[16 + e] = tot; meta[32 + e] = running; }
    running += tot;
  }
}

// ---- placement via block-local LDS cursors ---------------------------------
__global__ __launch_bounds__(256) void place_k(
    const int* __restrict__ top2, const float2* __restrict__ gate2,
    const int* __restrict__ b32, int* __restrict__ tok, int* __restrict__ ae,
    float* __restrict__ agv, int* __restrict__ inv)
{
  __shared__ int cur[8];
  if (threadIdx.x < 8) cur[threadIdx.x] = b32[blockIdx.x * 8 + threadIdx.x];
  __syncthreads();
  const int t = blockIdx.x * 256 + threadIdx.x;
  const int p = top2[t];
  const float2 gg = gate2[t];
  const int e1 = p & 255, e2 = (p >> 8) & 255;
  const int s1 = atomicAdd(&cur[e1], 1);
  tok[s1] = t; ae[s1] = e1; agv[s1] = gg.x; inv[2 * t] = s1;
  const int s2 = atomicAdd(&cur[e2], 1);
  tok[s2] = t; ae[s2] = e2; agv[s2] = gg.y; inv[2 * t + 1] = s2;
}

// block -> (expert, tile)
__device__ __forceinline__ bool find_tile(const int* meta, int tm,
                                          int& e, int& base, int& valid)
{
  for (e = 0; e < NE; e++){
    const int cnt = meta[16 + e];
    const int nt = (cnt + 127) >> 7;
    if (tm < nt){
      const int r0 = tm << 7;
      base = meta[32 + e] + r0;
      valid = cnt - r0;
      return true;
    }
    tm -= nt;
  }
  return false;
}

// ---- grouped GEMM1: 128x128 tile, 8 waves, double-buffered single-barrier --
// Hc = g * gelu(x @ w1_e + b1_e)
__global__ __launch_bounds__(512, 4) void gemm1g_k(
    const void* xq, const void* b1q, const __bf16* __restrict__ conv,
    const int* __restrict__ meta, const int* __restrict__ tok,
    const float* __restrict__ agv, __bf16* __restrict__ Hc)
{
  const int md = meta[0];
  const __bf16* X  = md ? (const __bf16*)xq : conv + CO_X;
  const __bf16* WT = conv + CO_W1;   // w1T [8][512][1024]
  const __bf16* bb = md ? (const __bf16*)b1q : conv + CO_B1;

  int e, base, valid;
  if (!find_tile(meta, blockIdx.x, e, base, valid)) return;
  const int n0 = blockIdx.y * 128;

  __shared__ __attribute__((aligned(16))) __bf16 As[2][128 * 32];
  __shared__ __attribute__((aligned(16))) __bf16 Bs[2][128 * 32];

  const int tid = threadIdx.x;
  const int wv = tid >> 6, lane = tid & 63;
  const int q = lane >> 4, ln = lane & 15;
  const int wm = (wv >> 2) * 64, wn = (wv & 3) * 32;   // 2x4 wave grid, 64x32 each
  f32x4 acc[4][2] = {};

  // staging: one 16B async load per thread per tile (lane-linear LDS)
  const int sr = tid >> 2, sc = (tid & 3) * 8;          // row 0..127, chunk 0..3
  const int tr = tok[base + ((sr < valid) ? sr : 0)];
  const __bf16* Ag = X + (size_t)tr * DM + sc;
  const __bf16* Bg = WT + (size_t)e * (DE * DM) + (size_t)(n0 + sr) * DM + sc;

  async_ld16(Ag, &As[0][tid * 8]);
  async_ld16(Bg, &Bs[0][tid * 8]);
  __syncthreads();

  int cr = 0;
  for (int k0 = 0; k0 < DM; k0 += 32){
    const int k1 = k0 + 32;
    if (k1 < DM){                       // prefetch next tile into other buffer
      async_ld16(Ag + k1, &As[cr ^ 1][tid * 8]);
      async_ld16(Bg + k1, &Bs[cr ^ 1][tid * 8]);
    }
    bf16x8 af[4], bfr[2];
    #pragma unroll
    for (int mi = 0; mi < 4; mi++)
      af[mi] = *(const bf16x8*)&As[cr][(wm + mi * 16 + ln) * 32 + q * 8];
    #pragma unroll
    for (int ni = 0; ni < 2; ni++)
      bfr[ni] = *(const bf16x8*)&Bs[cr][(wn + ni * 16 + ln) * 32 + q * 8];
    #pragma unroll
    for (int mi = 0; mi < 4; mi++)
      #pragma unroll
      for (int ni = 0; ni < 2; ni++)
        acc[mi][ni] = __builtin_amdgcn_mfma_f32_16x16x32_bf16(
            af[mi], bfr[ni], acc[mi][ni], 0, 0, 0);
    __syncthreads();                    // drains vmcnt(0)+lgkmcnt(0): next buf ready
    cr ^= 1;
  }

  const int coln = n0 + wn;
  float bset[2];
  #pragma unroll
  for (int ni = 0; ni < 2; ni++)
    bset[ni] = (float)bb[e * DE + coln + ni * 16 + ln];
  #pragma unroll
  for (int mi = 0; mi < 4; mi++){
    #pragma unroll
    for (int r = 0; r < 4; r++){
      const int row = wm + mi * 16 + q * 4 + r;
      if (row < valid){
        const int slot = base + row;
        const float g = agv[slot];
        #pragma unroll
        for (int ni = 0; ni < 2; ni++){
          float v = acc[mi][ni][r] + bset[ni];
          float h = 0.5f * v * (1.0f + erff(v * 0.70710678118654752f));
          Hc[(size_t)slot * DE + coln + ni * 16 + ln] = (__bf16)(g * h);
        }
      }
    }
  }
}

// ---- grouped GEMM2: 128x128 tile, 8 waves, double-buffered: Oc = Hc @ w2_e -
__global__ __launch_bounds__(512, 4) void gemm2g_k(
    const __bf16* __restrict__ Hc, const __bf16* __restrict__ conv,
    const int* __restrict__ meta, __bf16* __restrict__ Oc)
{
  const __bf16* WT = conv + CO_W2;   // w2T [8][1024][512]

  int e, base, valid;
  if (!find_tile(meta, blockIdx.x, e, base, valid)) return;
  const int n0 = blockIdx.y * 128;

  __shared__ __attribute__((aligned(16))) __bf16 As[2][128 * 32];
  __shared__ __attribute__((aligned(16))) __bf16 Bs[2][128 * 32];

  const int tid = threadIdx.x;
  const int wv = tid >> 6, lane = tid & 63;
  const int q = lane >> 4, ln = lane & 15;
  const int wm = (wv >> 2) * 64, wn = (wv & 3) * 32;
  f32x4 acc[4][2] = {};

  const int sr = tid >> 2, sc = (tid & 3) * 8;
  const int rc = (sr < valid) ? sr : 0;
  const __bf16* Ag = Hc + (size_t)(base + rc) * DE + sc;
  const __bf16* Bg = WT + (size_t)e * (DM * DE) + (size_t)(n0 + sr) * DE + sc;

  async_ld16(Ag, &As[0][tid * 8]);
  async_ld16(Bg, &Bs[0][tid * 8]);
  __syncthreads();

  int cr = 0;
  for (int k0 = 0; k0 < DE; k0 += 32){
    const int k1 = k0 + 32;
    if (k1 < DE){
      async_ld16(Ag + k1, &As[cr ^ 1][tid * 8]);
      async_ld16(Bg + k1, &Bs[cr ^ 1][tid * 8]);
    }
    bf16x8 af[4], bfr[2];
    #pragma unroll
    for (int mi = 0; mi < 4; mi++)
      af[mi] = *(const bf16x8*)&As[cr][(wm + mi * 16 + ln) * 32 + q * 8];
    #pragma unroll
    for (int ni = 0; ni < 2; ni++)
      bfr[ni] = *(const bf16x8*)&Bs[cr][(wn + ni * 16 + ln) * 32 + q * 8];
    #pragma unroll
    for (int mi = 0; mi < 4; mi++)
      #pragma unroll
      for (int ni = 0; ni < 2; ni++)
        acc[mi][ni] = __builtin_amdgcn_mfma_f32_16x16x32_bf16(
            af[mi], bfr[ni], acc[mi][ni], 0, 0, 0);
    __syncthreads();
    cr ^= 1;
  }

  #pragma unroll
  for (int mi = 0; mi < 4; mi++){
    #pragma unroll
    for (int r = 0; r < 4; r++){
      const int row = wm + mi * 16 + q * 4 + r;
      if (row < valid){
        const int slot = base + row;
        #pragma unroll
        for (int ni = 0; ni < 2; ni++)
          Oc[(size_t)slot * DM + n0 + wn + ni * 16 + ln] = (__bf16)acc[mi][ni][r];
      }
    }
  }
}

// ---- combine: out[t] = Oc[s1] + Oc[s2] + g1*b2[e1] + g2*b2[e2] -------------
__global__ __launch_bounds__(256) void combine_k(
    const __bf16* __restrict__ Oc, const int* __restrict__ inv,
    const int* __restrict__ ae, const float* __restrict__ agv,
    const void* b2q, const int* __restrict__ meta, void* out)
{
  const int md = meta[0];
  const int t = blockIdx.x;
  const int s1 = inv[2 * t], s2 = inv[2 * t + 1];
  const int e1 = ae[s1], e2 = ae[s2];
  const float g1 = agv[s1], g2 = agv[s2];
  const int c = threadIdx.x * 4;

  bf16x4 o1 = *(const bf16x4*)(Oc + (size_t)s1 * DM + c);
  bf16x4 o2 = *(const bf16x4*)(Oc + (size_t)s2 * DM + c);
  f32x4 bv1 = ld4(b2q, (size_t)e1 * DM + c, md);
  f32x4 bv2 = ld4(b2q, (size_t)e2 * DM + c, md);
  f32x4 rr;
  #pragma unroll
  for (int j = 0; j < 4; j++)
    rr[j] = (float)o1[j] + (float)o2[j] + g1 * bv1[j] + g2 * bv2[j];

  if (md){
    bf16x4 ob;
    #pragma unroll
    for (int j = 0; j < 4; j++) ob[j] = (__bf16)rr[j];
    *(bf16x4*)((__bf16*)out + (size_t)t * DM + c) = ob;
  } else {
    *(f32x4*)((float*)out + (size_t)t * DM + c) = rr;
  }
}

extern "C" void kernel_launch(void* const* d_in, const int* in_sizes, int n_in,
                              void* d_out, int out_size, void* d_ws, size_t ws_size,
                              hipStream_t stream)
{
  char* ws = (char*)d_ws;
  int*    meta  = (int*)ws;
  float2* gate2 = (float2*)(ws + WS_GATE2);
  int*    b32   = (int*)(ws + WS_B32);
  int*    top2  = (int*)(ws + WS_TOP2);
  int*    tok   = (int*)(ws + WS_TOK);
  int*    ae    = (int*)(ws + WS_AE);
  float*  agv   = (float*)(ws + WS_AG);
  int*    inv   = (int*)(ws + WS_INV);
  __bf16* conv  = (__bf16*)(ws + WS_CONV);
  __bf16* Hc    = (__bf16*)(ws + WS_HC);
  __bf16* Oc    = (__bf16*)(ws + WS_OC);

  detect_k<<<1, 256, 0, stream>>>(d_in[0], d_in[5], meta, b32);
  transp_k<<<8192, 256, 0, stream>>>(d_in[1], d_in[3], conv, meta);
  convert_k<<<28, 256, 0, stream>>>(
      (const float*)d_in[2], (const float*)d_in[4], (const float*)d_in[5],
      (const float*)d_in[6], conv, meta);
  route_k<<<T_TOK / 16, 256, 0, stream>>>(d_in[0], d_in[5], d_in[6], meta,
                                          conv, gate2, top2, b32);
  offsets_k<<<1, 64, 0, stream>>>(meta, b32);
  place_k<<<T_TOK / 256, 256, 0, stream>>>(top2, gate2, b32, tok, ae, agv, inv);
  gemm1g_k<<<dim3(136, 4), 512, 0, stream>>>(d_in[0], d_in[2], conv, meta,
                                             tok, agv, Hc);
  gemm2g_k<<<dim3(136, 8), 512, 0, stream>>>(Hc, conv, meta, Oc);
  combine_k<<<T_TOK, 256, 0, stream>>>(Oc, inv, ae, agv, d_in[4], meta, d_out);
}